// Round 5
// baseline (719.566 us; speedup 1.0000x reference)
//
#include <hip/hip_runtime.h>

typedef __attribute__((ext_vector_type(8))) short bfrag;          // 8 bf16 (4 VGPRs)
typedef __attribute__((ext_vector_type(8))) unsigned short us8;
typedef __attribute__((ext_vector_type(16))) float f16v;          // 32x32 MFMA acc

__device__ __forceinline__ unsigned short f2bf(float f) {
  union { float f; unsigned u; } v; v.f = f;
  unsigned u = v.u;
  return (unsigned short)((u + 0x7fffu + ((u >> 16) & 1u)) >> 16);  // RNE
}
__device__ __forceinline__ unsigned pkbf(float a, float b) {
  return (unsigned)f2bf(a) | ((unsigned)f2bf(b) << 16);
}
__device__ __forceinline__ unsigned pk2f(float a, float b) {       // round-half-up pack
  union { float f; unsigned u; } ua, ub; ua.f = a; ub.f = b;
  return ((ua.u + 0x8000u) >> 16) | ((ub.u + 0x8000u) & 0xffff0000u);
}
__device__ __forceinline__ float wred(float v) {
#pragma unroll
  for (int m = 32; m >= 1; m >>= 1) v += __shfl_xor(v, m, 64);
  return v;
}
// async global->LDS DMA, 16B per lane (global source may be per-lane scattered;
// LDS dest is wave-uniform base + lane*16).
__device__ __forceinline__ void dma16(const void* g, void* l) {
  __builtin_amdgcn_global_load_lds(
      (const __attribute__((address_space(1))) void*)g,
      (__attribute__((address_space(3))) void*)l, 16, 0, 0);
}

// ---------------------------------------------------------------------------
// Batched transpose fp32 -> bf16: out[z][j][i] = bf16(in[z][i][j]), i<R, j<C.
// grid: (R/64, C/64, Z), block 256.  (Wo only)
// ---------------------------------------------------------------------------
__global__ __launch_bounds__(256) void transp_f2b(
    const float* __restrict__ in, short* __restrict__ out, int R, int Cc)
{
  long zofs = (long)blockIdx.z * R * Cc;
  const float* inz = in + zofs;
  unsigned short* oz = (unsigned short*)out + zofs;
  int i0 = blockIdx.x * 64, j0 = blockIdx.y * 64;
  int l = threadIdx.x & 63, ty = threadIdx.x >> 6;
  int i = i0 + l;
#pragma unroll
  for (int itr = 0; itr < 2; ++itr) {
    int j = j0 + ty * 16 + itr * 8;
    const float* p = inz + (long)i * Cc + j;
    float4 v0 = *(const float4*)(p);
    float4 v1 = *(const float4*)(p + 4);
    float vv[8] = {v0.x, v0.y, v0.z, v0.w, v1.x, v1.y, v1.z, v1.w};
#pragma unroll
    for (int s = 0; s < 8; ++s) oz[(long)(j + s) * R + i] = f2bf(vv[s]);
  }
}

// ---------------------------------------------------------------------------
// Wq/Wk/Wv transpose in one launch: 12 z-slices of 256x256.
// out = WqT base; WkT/WvT contiguous after it. grid (4,4,12), block 256.
// ---------------------------------------------------------------------------
__global__ __launch_bounds__(256) void transp_w3(
    const float* __restrict__ Wq, const float* __restrict__ Wk,
    const float* __restrict__ Wv, short* __restrict__ out)
{
  int z = blockIdx.z;   // 0..11: [0,4)=Wq, [4,8)=Wk, [8,12)=Wv
  const float* inz = (z < 4 ? Wq : (z < 8 ? Wk : Wv)) + (long)(z & 3) * 65536;
  unsigned short* oz = (unsigned short*)out + (long)z * 65536;
  int i0 = blockIdx.x * 64, j0 = blockIdx.y * 64;
  int l = threadIdx.x & 63, ty = threadIdx.x >> 6;
  int i = i0 + l;
#pragma unroll
  for (int itr = 0; itr < 2; ++itr) {
    int j = j0 + ty * 16 + itr * 8;
    const float* p = inz + (long)i * 256 + j;
    float4 v0 = *(const float4*)(p);
    float4 v1 = *(const float4*)(p + 4);
    float vv[8] = {v0.x, v0.y, v0.z, v0.w, v1.x, v1.y, v1.z, v1.w};
#pragma unroll
    for (int s = 0; s < 8; ++s) oz[(long)(j + s) * 256 + i] = f2bf(vv[s]);
  }
}

// ---------------------------------------------------------------------------
// img transpose, fused pos-add: from img_emb [B][256][4096] fp32 produce
//   imgT[b][n][c]    = bf16(img)
//   imgPosT[b][n][c] = bf16(img + pos[n][c])
// grid (4, 64, 4), block 256.
// ---------------------------------------------------------------------------
__global__ __launch_bounds__(256) void transp_img(
    const float* __restrict__ in, const float* __restrict__ pos,
    short* __restrict__ outT, short* __restrict__ outPosT)
{
  long zofs = (long)blockIdx.z * (256L * 4096L);
  const float* inz = in + zofs;
  unsigned short* o1 = (unsigned short*)outT + zofs;
  unsigned short* o2 = (unsigned short*)outPosT + zofs;
  int i0 = blockIdx.x * 64, j0 = blockIdx.y * 64;
  int l = threadIdx.x & 63, ty = threadIdx.x >> 6;
  int i = i0 + l;
#pragma unroll
  for (int itr = 0; itr < 2; ++itr) {
    int j = j0 + ty * 16 + itr * 8;
    const float* p = inz + (long)i * 4096 + j;
    float4 v0 = *(const float4*)(p);
    float4 v1 = *(const float4*)(p + 4);
    float vv[8] = {v0.x, v0.y, v0.z, v0.w, v1.x, v1.y, v1.z, v1.w};
#pragma unroll
    for (int s = 0; s < 8; ++s) {
      float x = vv[s];
      long o = (long)(j + s) * 256 + i;
      o1[o] = f2bf(x);
      o2[o] = f2bf(x + pos[o]);   // pos[(j+s)*256+i]
    }
  }
}

// ---------------------------------------------------------------------------
// fp32 -> bf16 cast (point_emb). grid 2048, block 256, 8 elems/thread.
// ---------------------------------------------------------------------------
__global__ __launch_bounds__(256) void cast_f2b(
    const float* __restrict__ in, short* __restrict__ out)
{
  long i = ((long)blockIdx.x * 256 + threadIdx.x) * 8;
  float4 v0 = *(const float4*)(in + i);
  float4 v1 = *(const float4*)(in + i + 4);
  uint4 st;
  st.x = pkbf(v0.x, v0.y);
  st.y = pkbf(v0.z, v0.w);
  st.z = pkbf(v1.x, v1.y);
  st.w = pkbf(v1.z, v1.w);
  *(uint4*)((unsigned short*)out + i) = st;
}

// ---------------------------------------------------------------------------
// QKV GEMM (pure bf16, compile-time shape M=4096 N=256 K=256, Hq=4):
//   C[z] = bf16((A[z/4] @ Bt[z%4]^T + bias[z%4]) * scale)
// A bf16 [B][4096][256]; Bt bf16 [4][256][256]. transC: store C^T vectorized.
// block 256, tile 128x64, grid (32, 4, 16).
// ---------------------------------------------------------------------------
__global__ __launch_bounds__(256) void gemm_qkv(
    const short* __restrict__ A, const short* __restrict__ Bt,
    const float* __restrict__ bias, short* __restrict__ Co,
    float scale, int transC)
{
  int z = blockIdx.z;
  const short* Az = A + (long)(z >> 2) * 1048576;
  const short* Btz = Bt + (long)(z & 3) * 65536;
  const float* biasz = bias + (long)(z & 3) * 256;
  short* Cz = Co + (long)z * 1048576;

  int tid = threadIdx.x;
  int w = tid >> 6, lane = tid & 63;
  int half = lane >> 5, ln = lane & 31;
  int wm = w & 1, wn = w >> 1;
  int row0 = blockIdx.x * 128 + wm * 64;
  int col0 = blockIdx.y * 64 + wn * 32;

  f16v acc0, acc1;
#pragma unroll
  for (int i = 0; i < 16; ++i) { acc0[i] = 0.f; acc1[i] = 0.f; }

  const short* ap0 = Az + (long)(row0 + ln) * 256 + half * 8;
  const short* ap1 = Az + (long)(row0 + 32 + ln) * 256 + half * 8;
  const short* bp  = Btz + (long)(col0 + ln) * 256 + half * 8;

#pragma unroll
  for (int kt = 0; kt < 16; ++kt) {
    bfrag a0 = *(const bfrag*)(ap0 + kt * 16);
    bfrag a1 = *(const bfrag*)(ap1 + kt * 16);
    bfrag bb = *(const bfrag*)(bp + kt * 16);
    acc0 = __builtin_amdgcn_mfma_f32_32x32x16_bf16(a0, bb, acc0, 0, 0, 0);
    acc1 = __builtin_amdgcn_mfma_f32_32x32x16_bf16(a1, bb, acc1, 0, 0, 0);
  }

  int col = col0 + ln;
  float bv = biasz[col];
  if (transC) {
#pragma unroll
    for (int t = 0; t < 2; ++t) {
      int rbase = row0 + t * 32;
#pragma unroll
      for (int g = 0; g < 4; ++g) {
        float v0 = ((t ? acc1[4*g+0] : acc0[4*g+0]) + bv) * scale;
        float v1 = ((t ? acc1[4*g+1] : acc0[4*g+1]) + bv) * scale;
        float v2 = ((t ? acc1[4*g+2] : acc0[4*g+2]) + bv) * scale;
        float v3 = ((t ? acc1[4*g+3] : acc0[4*g+3]) + bv) * scale;
        uint2 st;
        st.x = pkbf(v0, v1);
        st.y = pkbf(v2, v3);
        *(uint2*)&((unsigned short*)Cz)[(long)col * 4096 + rbase + 8 * g + 4 * half] = st;
      }
    }
  } else {
#pragma unroll
    for (int t = 0; t < 2; ++t) {
      int rbase = row0 + t * 32;
#pragma unroll
      for (int r = 0; r < 16; ++r) {
        float av = t ? acc1[r] : acc0[r];
        int rr = rbase + (r & 3) + 8 * (r >> 2) + 4 * half;
        ((unsigned short*)Cz)[(long)rr * 256 + col] = f2bf((av + bv) * scale);
      }
    }
  }
}

// ---------------------------------------------------------------------------
// Output projection (compile-time shape M=16384 N=256 K=1024):
// emb[r][col] = att(head-major bf16) @ WoT^T + bo + resid, fp32 output.
// A: [B][H][4096][256] bf16 (r=b*4096+n, k=h*256+e). grid (128,4,1), block 256.
// ---------------------------------------------------------------------------
__global__ __launch_bounds__(256) void gemm_out(
    const short* __restrict__ A, const short* __restrict__ Bt,
    const float* __restrict__ bias, float* __restrict__ Co,
    const float* __restrict__ resid)
{
  int tid = threadIdx.x;
  int w = tid >> 6, lane = tid & 63;
  int half = lane >> 5, ln = lane & 31;
  int wm = w & 1, wn = w >> 1;
  int row0 = blockIdx.x * 128 + wm * 64;
  int col0 = blockIdx.y * 64 + wn * 32;

  f16v acc0, acc1;
#pragma unroll
  for (int i = 0; i < 16; ++i) { acc0[i] = 0.f; acc1[i] = 0.f; }

  int r0 = row0 + ln, r1 = row0 + 32 + ln;
  long a0base = (long)(r0 >> 12) * 4194304 + (long)(r0 & 4095) * 256 + half * 8;
  long a1base = (long)(r1 >> 12) * 4194304 + (long)(r1 & 4095) * 256 + half * 8;
  const short* bp = Bt + (long)(col0 + ln) * 1024 + half * 8;

  for (int kh = 0; kh < 4; ++kh) {          // head-major K blocks
    const short* a0p = A + a0base + (long)kh * 1048576;
    const short* a1p = A + a1base + (long)kh * 1048576;
    const short* bkp = bp + kh * 256;
#pragma unroll
    for (int kt = 0; kt < 16; ++kt) {
      bfrag a0 = *(const bfrag*)(a0p + kt * 16);
      bfrag a1 = *(const bfrag*)(a1p + kt * 16);
      bfrag bb = *(const bfrag*)(bkp + kt * 16);
      acc0 = __builtin_amdgcn_mfma_f32_32x32x16_bf16(a0, bb, acc0, 0, 0, 0);
      acc1 = __builtin_amdgcn_mfma_f32_32x32x16_bf16(a1, bb, acc1, 0, 0, 0);
    }
  }

  int col = col0 + ln;
  float bv = bias[col];
#pragma unroll
  for (int t = 0; t < 2; ++t) {
    int rbase = row0 + t * 32;
#pragma unroll
    for (int r = 0; r < 16; ++r) {
      float av = t ? acc1[r] : acc0[r];
      int rr = rbase + (r & 3) + 8 * (r >> 2) + 4 * half;
      Co[(long)rr * 256 + col] = av + bv + resid[(long)rr * 256 + col];
    }
  }
}

// ---------------------------------------------------------------------------
// Flash attention. ROUND 5: r4's DMA staging kept; block re-split 512thr/8w
// -> 256thr/4w (128 q-rows), grid 512 => 2 co-resident blocks per CU.
// r3 tried this and died on registers (reg-staging ballooned arch VGPRs to
// 172 -> 1 wave/SIMD -> blocks serialized); with DMA staging arch stays
// ~130 so both blocks fit (LDS 2x64KB<=160, regs 2x~280<=2048/SIMD).
// The two blocks' barrier cadences decouple: one block's MFMA covers the
// other's softmax/barrier-skew — the ~40% unaccounted stall in r4's iter.
// Each wave now DMAs 4 K-chunks + 4 V-chunks per tile (was 2+2).
// ---------------------------------------------------------------------------
__global__ __launch_bounds__(256, 2) void attn_kernel(
    const short* __restrict__ Qg, const short* __restrict__ Kg,
    const short* __restrict__ Vtg, short* __restrict__ attc)
{
  __shared__ char smem[65536];   // buf b at b*32768: [K 16KB | V 16KB]
  int bx = blockIdx.x;
  int bh = bx & 15, qg = bx >> 4;          // head-major XCD swizzle (load-bearing)
  int tid = threadIdx.x;
  int w = tid >> 6, lane = tid & 63;       // w in [0,4)
  int half = lane >> 5, ln = lane & 31;
  int q0 = qg * 128 + w * 32;              // qg in [0,32)

  // Q fragments (B-operand): lane ln holds q-row q0+ln, k = 16kt + 8half + j.
  bfrag qf[16];
  {
    const short* qrow = Qg + ((long)bh * 4096 + q0 + ln) * 256 + half * 8;
#pragma unroll
    for (int kt = 0; kt < 16; ++kt) qf[kt] = *(const bfrag*)(qrow + kt * 16);
  }

  // MFMA-read LDS byte offsets (unchanged swizzle)
  int koff[4], voff[2];
#pragma unroll
  for (int m = 0; m < 4; ++m) koff[m] = ((ln ^ (2 * m + half)) * 16) + half * 512;
#pragma unroll
  for (int kp = 0; kp < 2; ++kp) {
    int ck = 2 * kp + half;
    voff[kp] = 16384 + ck * 4096 + ((ln ^ (ck << 1)) * 16);
  }

  // DMA source offsets: wave w stages LDS 1KB chunks wc = 4w+p (p=0..3) of
  // each tile half. Inverse swizzle on the global side:
  //   K chunk wc: c = 2*wc + half, row = ln^(c&7)  -> gbyte = row*512 + c*16
  //   V chunk wc: ck = wc>>2 = w, e = ((wc&3)*64+lane)^(w<<1)
  //                                 -> gbyte = e*8192 + w*16
  int kgl[4], vgl[4];
#pragma unroll
  for (int p = 0; p < 4; ++p) {
    int wc = 4 * w + p;
    int c = 2 * wc + half;
    kgl[p] = (ln ^ (c & 7)) * 512 + c * 16;
    int e = (p * 64 + lane) ^ (w << 1);
    vgl[p] = e * 8192 + w * 16;
  }
  int ldsk = 4 * w * 1024;             // wave's K dest base (chunk 4w)
  int ldsv = 16384 + 4 * w * 1024;     // wave's V dest base
  const char* kgp = (const char*)Kg + (long)bh * 2097152;   // += 16384 per tile
  const char* vgp = (const char*)Vtg + (long)bh * 2097152;  // += 64 per tile

  f16v O[8];
#pragma unroll
  for (int t = 0; t < 8; ++t)
#pragma unroll
    for (int r = 0; r < 16; ++r) O[t][r] = 0.f;

  float l_run = 0.f;
  union { bfrag f; unsigned u[4]; } bb[2];

  // prologue: DMA K_0 into buf0
#pragma unroll
  for (int p = 0; p < 4; ++p) dma16(kgp + kgl[p], smem + ldsk + p * 1024);
  kgp += 16384;

  // iter 0: S(K_0) from buf0, DMA K_1 + V_0 into buf1 (no V-MFMA yet)
  __syncthreads();
#pragma unroll
  for (int p = 0; p < 4; ++p) dma16(kgp + kgl[p], smem + 32768 + ldsk + p * 1024);
  kgp += 16384;
#pragma unroll
  for (int p = 0; p < 4; ++p) dma16(vgp + vgl[p], smem + 32768 + ldsv + p * 1024);
  vgp += 64;
  {
    f16v S;
#pragma unroll
    for (int r = 0; r < 16; ++r) S[r] = 0.f;
#pragma unroll
    for (int kt = 0; kt < 16; ++kt) {
      bfrag a = *(const bfrag*)(smem + koff[kt & 3] + kt * 1024);
      S = __builtin_amdgcn_mfma_f32_32x32x16_bf16(a, qf[kt], S, 0, 0, 0);
    }
    float ss = 0.f;
#pragma unroll
    for (int r = 0; r < 16; ++r) { float e = exp2f(S[r] - 8.f); S[r] = e; ss += e; }
    l_run += ss;
#pragma unroll
    for (int kp = 0; kp < 2; ++kp) {
      unsigned pk0 = pk2f(S[8 * kp + 0], S[8 * kp + 1]);
      unsigned pk1 = pk2f(S[8 * kp + 2], S[8 * kp + 3]);
      unsigned pk2 = pk2f(S[8 * kp + 4], S[8 * kp + 5]);
      unsigned pk3 = pk2f(S[8 * kp + 6], S[8 * kp + 7]);
      unsigned o0 = (unsigned)__shfl_xor((int)pk0, 32);
      unsigned o1 = (unsigned)__shfl_xor((int)pk1, 32);
      unsigned o2 = (unsigned)__shfl_xor((int)pk2, 32);
      unsigned o3 = (unsigned)__shfl_xor((int)pk3, 32);
      bb[kp].u[0] = half ? o2 : pk0;
      bb[kp].u[1] = half ? o3 : pk1;
      bb[kp].u[2] = half ? pk2 : o0;
      bb[kp].u[3] = half ? pk3 : o1;
    }
  }

// one pipelined iteration with compile-time buffer parity.
// reads K_t (buf BUF) + V_{t-1} (buf BUF); DMAs K_{t+1}+V_t into buf BUF^1.
// the barrier at the top drains last iter's DMAs (implicit vmcnt(0)).
#define ATTN_ITER(BUF, KLOAD)                                                  \
  {                                                                            \
    __syncthreads();                                                           \
    if (KLOAD) {                                                               \
      _Pragma("unroll")                                                        \
      for (int p = 0; p < 4; ++p)                                              \
        dma16(kgp + kgl[p], smem + ((BUF) ^ 1) * 32768 + ldsk + p * 1024);     \
      kgp += 16384;                                                            \
    }                                                                          \
    _Pragma("unroll")                                                          \
    for (int p = 0; p < 4; ++p)                                                \
      dma16(vgp + vgl[p], smem + ((BUF) ^ 1) * 32768 + ldsv + p * 1024);       \
    vgp += 64;                                                                 \
    f16v S;                                                                    \
    _Pragma("unroll")                                                          \
    for (int r = 0; r < 16; ++r) S[r] = 0.f;                                   \
    _Pragma("unroll")                                                          \
    for (int kt = 0; kt < 16; ++kt) {                                          \
      bfrag a = *(const bfrag*)(smem + koff[kt & 3] + ((BUF)*32768 + kt*1024));\
      S = __builtin_amdgcn_mfma_f32_32x32x16_bf16(a, qf[kt], S, 0, 0, 0);      \
      bfrag va = *(const bfrag*)(smem + voff[kt >> 3] +                        \
                                 ((BUF)*32768 + (kt & 7) * 512));              \
      O[kt & 7] = __builtin_amdgcn_mfma_f32_32x32x16_bf16(va, bb[kt >> 3].f,   \
                                                          O[kt & 7], 0, 0, 0); \
    }                                                                          \
    float ss = 0.f;                                                            \
    _Pragma("unroll")                                                          \
    for (int r = 0; r < 16; ++r) { float e = exp2f(S[r] - 8.f); S[r] = e; ss += e; } \
    l_run += ss;                                                               \
    _Pragma("unroll")                                                          \
    for (int kp = 0; kp < 2; ++kp) {                                           \
      unsigned pk0 = pk2f(S[8 * kp + 0], S[8 * kp + 1]);                       \
      unsigned pk1 = pk2f(S[8 * kp + 2], S[8 * kp + 3]);                       \
      unsigned pk2 = pk2f(S[8 * kp + 4], S[8 * kp + 5]);                       \
      unsigned pk3 = pk2f(S[8 * kp + 6], S[8 * kp + 7]);                       \
      unsigned o0 = (unsigned)__shfl_xor((int)pk0, 32);                        \
      unsigned o1 = (unsigned)__shfl_xor((int)pk1, 32);                        \
      unsigned o2 = (unsigned)__shfl_xor((int)pk2, 32);                        \
      unsigned o3 = (unsigned)__shfl_xor((int)pk3, 32);                        \
      bb[kp].u[0] = half ? o2 : pk0;                                           \
      bb[kp].u[1] = half ? o3 : pk1;                                           \
      bb[kp].u[2] = half ? pk2 : o0;                                           \
      bb[kp].u[3] = half ? pk3 : o1;                                           \
    }                                                                          \
  }

  // t = 1..126 as 63 static-parity pairs, then t = 127.
  for (int tp = 0; tp < 63; ++tp) {
    ATTN_ITER(1, 1)     // odd t
    ATTN_ITER(0, 1)     // even t
  }
  ATTN_ITER(1, 0)       // t = 127: no K prefetch; V_127 DMA'd into buf0
#undef ATTN_ITER

  // epilogue: V-MFMA for tile 127 (buf0 V half)
  __syncthreads();
#pragma unroll
  for (int kp = 0; kp < 2; ++kp) {
#pragma unroll
    for (int mt = 0; mt < 8; ++mt) {
      bfrag va = *(const bfrag*)(smem + voff[kp] + mt * 512);
      O[mt] = __builtin_amdgcn_mfma_f32_32x32x16_bf16(va, bb[kp].f, O[mt], 0, 0, 0);
    }
  }

  // attc[bh][q][e] = O^T[e][q]/l.  l = own-half + partner-half.
  l_run += __shfl_xor(l_run, 32);
  float rl = 1.0f / l_run;
  short* orow = attc + ((long)bh * 4096 + q0 + ln) * 256;
#pragma unroll
  for (int mt = 0; mt < 8; ++mt) {
#pragma unroll
    for (int g = 0; g < 4; ++g) {
      uint2 st;
      st.x = pkbf(O[mt][4 * g + 0] * rl, O[mt][4 * g + 1] * rl);
      st.y = pkbf(O[mt][4 * g + 2] * rl, O[mt][4 * g + 3] * rl);
      *(uint2*)(orow + mt * 32 + 8 * g + 4 * half) = st;
    }
  }
}

// ---------------------------------------------------------------------------
// FFN head (all fp32): 16 rows per 256-thr block, 4 rows per wave.
// x/h stored transposed in LDS ([k][4rows]) so one broadcast ds_read_b128
// feeds 4 rows; W1/W2 loads amortized 4x. Per-wave buffers -> no barriers.
// ---------------------------------------------------------------------------
__global__ __launch_bounds__(256) void ffn_kernel(
    const float* __restrict__ emb,
    const float* __restrict__ W1, const float* __restrict__ b1,
    const float* __restrict__ g1, const float* __restrict__ be1,
    const float* __restrict__ W2, const float* __restrict__ b2,
    const float* __restrict__ g2, const float* __restrict__ be2,
    const float* __restrict__ W3, const float* __restrict__ b3,
    float* __restrict__ act)
{
  __shared__ float xs[4][256][4];   // [wave][k][row]  16KB
  __shared__ float hs[4][128][4];   // [wave][k][row]   8KB
  int w = threadIdx.x >> 6, l = threadIdx.x & 63;
  int row0 = blockIdx.x * 16 + w * 4;
  const float* x = emb + (long)row0 * 256;

  // load 4 rows, store transposed: lane l owns positions 4l..4l+3
  {
    float xv[4][4];   // [i][row]
#pragma unroll
    for (int rr = 0; rr < 4; ++rr) {
      float4 t = *(const float4*)(x + rr * 256 + 4 * l);
      xv[0][rr] = t.x; xv[1][rr] = t.y; xv[2][rr] = t.z; xv[3][rr] = t.w;
    }
#pragma unroll
    for (int i = 0; i < 4; ++i) {
      float4 st = make_float4(xv[i][0], xv[i][1], xv[i][2], xv[i][3]);
      *(float4*)&xs[w][4 * l + i][0] = st;
    }
  }

  // layer 1: 128 outputs, lane l owns outputs 2l, 2l+1, 4 rows each
  float a0[4], a1[4];
  {
    float bb0 = b1[2 * l], bb1 = b1[2 * l + 1];
#pragma unroll
    for (int rr = 0; rr < 4; ++rr) { a0[rr] = bb0; a1[rr] = bb1; }
  }
  for (int k = 0; k < 256; ++k) {
    float w0 = W1[k * 128 + 2 * l], w1 = W1[k * 128 + 2 * l + 1];
    float4 xv = *(const float4*)&xs[w][k][0];
    a0[0] += xv.x * w0; a1[0] += xv.x * w1;
    a0[1] += xv.y * w0; a1[1] += xv.y * w1;
    a0[2] += xv.z * w0; a1[2] += xv.z * w1;
    a0[3] += xv.w * w0; a1[3] += xv.w * w1;
  }
  {
    float gg0 = g1[2 * l], gg1 = g1[2 * l + 1];
    float ee0 = be1[2 * l], ee1 = be1[2 * l + 1];
    float n0v[4], n1v[4];
#pragma unroll
    for (int rr = 0; rr < 4; ++rr) {
      float u0 = fmaxf(a0[rr], 0.f), u1 = fmaxf(a1[rr], 0.f);
      float s1 = wred(u0 + u1);
      float s2 = wred(u0 * u0 + u1 * u1);
      float mu = s1 * (1.f / 128.f);
      float var = fmaxf(s2 * (1.f / 128.f) - mu * mu, 0.f);
      float rs = rsqrtf(var + 1e-5f);
      n0v[rr] = (u0 - mu) * rs * gg0 + ee0;
      n1v[rr] = (u1 - mu) * rs * gg1 + ee1;
    }
    *(float4*)&hs[w][2 * l][0]     = make_float4(n0v[0], n0v[1], n0v[2], n0v[3]);
    *(float4*)&hs[w][2 * l + 1][0] = make_float4(n1v[0], n1v[1], n1v[2], n1v[3]);
  }

  // layer 2: 64 outputs, lane l owns output l, 4 rows
  float c0[4];
  {
    float bb2 = b2[l];
#pragma unroll
    for (int rr = 0; rr < 4; ++rr) c0[rr] = bb2;
  }
  for (int k = 0; k < 128; ++k) {
    float w2 = W2[k * 64 + l];
    float4 hv = *(const float4*)&hs[w][k][0];
    c0[0] += hv.x * w2;
    c0[1] += hv.y * w2;
    c0[2] += hv.z * w2;
    c0[3] += hv.w * w2;
  }
  {
    float gg2 = g2[l], ee2 = be2[l], w3 = W3[l], bb3 = b3[0];
#pragma unroll
    for (int rr = 0; rr < 4; ++rr) {
      float u = fmaxf(c0[rr], 0.f);
      float t1 = wred(u);
      float t2 = wred(u * u);
      float mu2 = t1 * (1.f / 64.f);
      float var2 = fmaxf(t2 * (1.f / 64.f) - mu2 * mu2, 0.f);
      float rs2 = rsqrtf(var2 + 1e-5f);
      float n2 = (u - mu2) * rs2 * gg2 + ee2;
      float tt = wred(n2 * w3);
      if (l == 0) {
        float r = tt + bb3;
        act[row0 + rr] = 1.f / (1.f + __expf(-r));
      }
    }
  }
}

// ---------------------------------------------------------------------------
extern "C" void kernel_launch(void* const* d_in, const int* in_sizes, int n_in,
                              void* d_out, int out_size, void* d_ws, size_t ws_size,
                              hipStream_t stream)
{
  const float* img_emb   = (const float*)d_in[0];
  const float* point_emb = (const float*)d_in[1];
  const float* Wq = (const float*)d_in[2];
  const float* bq = (const float*)d_in[3];
  const float* Wk = (const float*)d_in[4];
  const float* bk = (const float*)d_in[5];
  const float* Wv = (const float*)d_in[6];
  const float* bv = (const float*)d_in[7];
  const float* Wo = (const float*)d_in[8];
  const float* bo = (const float*)d_in[9];
  const float* pos = (const float*)d_in[10];
  const float* W1 = (const float*)d_in[11];
  const float* b1 = (const float*)d_in[12];
  const float* g1 = (const float*)d_in[13];
  const float* be1 = (const float*)d_in[14];
  const float* W2 = (const float*)d_in[15];
  const float* b2 = (const float*)d_in[16];
  const float* g2 = (const float*)d_in[17];
  const float* be2 = (const float*)d_in[18];
  const float* W3 = (const float*)d_in[19];
  const float* b3 = (const float*)d_in[20];

  // ws layout (111.1 MB), all internal tensors bf16.
  // peT/imgT live INSIDE the VtB region: both are dead before the V-gemm
  // (the only writer of VtB) runs — stream order guarantees safety.
  // (Do NOT merge the three qkv GEMM launches: that ordering is load-bearing.)
  char* ws = (char*)d_ws;
  short* Qb      = (short*)(ws + 0);            // 33.55 MB [BH][4096][256]; attn out in-place
  short* Kb      = (short*)(ws + 33554432);     // 33.55 MB [BH][4096][256]
  short* VtB     = (short*)(ws + 67108864);     // 33.55 MB [BH][256][4096]
  short* peT     = (short*)(ws + 67108864);     //  8.39 MB [B][4096][256]  (dead after Q-gemm)
  short* imgT    = (short*)(ws + 75497472);     //  8.39 MB [B][4096][256]  (dead after K-gemm)
  short* imgPosT = (short*)(ws + 100663296);    //  8.39 MB [B][4096][256]
  short* WoT     = (short*)(ws + 109051904);    //  0.52 MB [256][1024]
  short* WqT     = (short*)(ws + 109576192);    //  0.13 MB [H][256][256]  (WkT,WvT follow)
  short* WkT     = (short*)(ws + 110100480);
  short* WvT     = (short*)(ws + 110624768);
  (void)WkT; (void)WvT;

  float* act_out = (float*)d_out;            // [B*N]
  float* emb_out = (float*)d_out + 16384;    // [B*N][256]

  const float qscale = 0.0901684400555602f;  // log2(e)/sqrt(256)

  // weight transposes (fp32 -> bf16): Wq/Wk/Wv in one launch, Wo separate
  transp_w3<<<dim3(4, 4, 12), 256, 0, stream>>>(Wq, Wk, Wv, WqT);
  transp_f2b<<<dim3(16, 4, 1), 256, 0, stream>>>(Wo, WoT, 1024, 256);
  // img transpose + fused pos-add; point_emb cast
  transp_img<<<dim3(4, 64, 4), 256, 0, stream>>>(img_emb, pos, imgT, imgPosT);
  cast_f2b<<<2048, 256, 0, stream>>>(point_emb, peT);

  // Q = (point_emb @ WqT + bq) * qscale      (reads peT — before VtB written)
  gemm_qkv<<<dim3(32, 4, 16), 256, 0, stream>>>(peT, WqT, bq, Qb, qscale, 0);
  // K = img @ WkT + bk                       (reads imgT — before VtB written)
  gemm_qkv<<<dim3(32, 4, 16), 256, 0, stream>>>(imgT, WqT + 262144, bk, Kb, 1.0f, 0);
  // V^T = ((img + pos) @ WvT + bv)^T         (reads imgPosT, writes VtB)
  gemm_qkv<<<dim3(32, 4, 16), 256, 0, stream>>>(imgPosT, WqT + 524288, bv, VtB, 1.0f, 1);

  // attention: reads Qb/Kb/VtB, writes att in-place over Qb ([BH][N][256])
  // 512 blocks x 256 thr: 2 co-resident 4-wave blocks per CU (anti-phase).
  attn_kernel<<<512, 256, 0, stream>>>(Qb, Kb, VtB, Qb);

  // emb = att @ Wo + bo + point_emb  (fp32 out)
  gemm_out<<<dim3(128, 4, 1), 256, 0, stream>>>(Qb, WoT, bo, emb_out, point_emb);

  // FFN head -> act (fp32)
  ffn_kernel<<<1024, 256, 0, stream>>>(emb_out, W1, b1, g1, be1, W2, b2, g2, be2,
                                       W3, b3, act_out);
}

// Round 6
// 638.133 us; speedup vs baseline: 1.1276x; 1.1276x over previous
//
#include <hip/hip_runtime.h>

typedef __attribute__((ext_vector_type(8))) short bfrag;          // 8 bf16 (4 VGPRs)
typedef __attribute__((ext_vector_type(8))) unsigned short us8;
typedef __attribute__((ext_vector_type(16))) float f16v;          // 32x32 MFMA acc

__device__ __forceinline__ unsigned short f2bf(float f) {
  union { float f; unsigned u; } v; v.f = f;
  unsigned u = v.u;
  return (unsigned short)((u + 0x7fffu + ((u >> 16) & 1u)) >> 16);  // RNE
}
__device__ __forceinline__ unsigned pkbf(float a, float b) {
  return (unsigned)f2bf(a) | ((unsigned)f2bf(b) << 16);
}
__device__ __forceinline__ unsigned pk2f(float a, float b) {       // round-half-up pack
  union { float f; unsigned u; } ua, ub; ua.f = a; ub.f = b;
  return ((ua.u + 0x8000u) >> 16) | ((ub.u + 0x8000u) & 0xffff0000u);
}
__device__ __forceinline__ float wred(float v) {
#pragma unroll
  for (int m = 32; m >= 1; m >>= 1) v += __shfl_xor(v, m, 64);
  return v;
}
// async global->LDS DMA, 16B per lane (global source may be per-lane scattered;
// LDS dest is wave-uniform base + lane*16).
__device__ __forceinline__ void dma16(const void* g, void* l) {
  __builtin_amdgcn_global_load_lds(
      (const __attribute__((address_space(1))) void*)g,
      (__attribute__((address_space(3))) void*)l, 16, 0, 0);
}

// ---------------------------------------------------------------------------
// Fused prep kernel (ROUND 6): replaces transp_w3 + transp_f2b(Wo) +
// transp_img + cast_f2b — 4 launches -> 1. Flattened 1-D grid, block 256:
//   [0, 2048)      : point_emb fp32->bf16 cast (peT)
//   [2048, 3072)   : img transpose + fused pos-add (imgT, imgPosT)
//   [3072, 3264)   : Wq/Wk/Wv 256x256 transposes (12 z-slices)
//   [3264, 3328)   : Wo 1024x256 transpose
// Per-block work identical to the r4 kernels (algorithms untouched).
// ---------------------------------------------------------------------------
__device__ __forceinline__ void transp64(
    const float* __restrict__ inz, unsigned short* __restrict__ oz,
    int R, int Cc, int i0, int j0, int tid)
{
  int l = tid & 63, ty = tid >> 6;
  int i = i0 + l;
#pragma unroll
  for (int itr = 0; itr < 2; ++itr) {
    int j = j0 + ty * 16 + itr * 8;
    const float* p = inz + (long)i * Cc + j;
    float4 v0 = *(const float4*)(p);
    float4 v1 = *(const float4*)(p + 4);
    float vv[8] = {v0.x, v0.y, v0.z, v0.w, v1.x, v1.y, v1.z, v1.w};
#pragma unroll
    for (int s = 0; s < 8; ++s) oz[(long)(j + s) * R + i] = f2bf(vv[s]);
  }
}

__global__ __launch_bounds__(256) void prep_kernel(
    const float* __restrict__ point_emb, short* __restrict__ peT,
    const float* __restrict__ img_emb, const float* __restrict__ pos,
    short* __restrict__ imgT, short* __restrict__ imgPosT,
    const float* __restrict__ Wq, const float* __restrict__ Wk,
    const float* __restrict__ Wv, short* __restrict__ WqT,
    const float* __restrict__ Wo, short* __restrict__ WoT)
{
  int b = blockIdx.x;
  int tid = threadIdx.x;

  if (b < 2048) {
    // ---- point_emb cast: 8 elems/thread ----
    long i = ((long)b * 256 + tid) * 8;
    float4 v0 = *(const float4*)(point_emb + i);
    float4 v1 = *(const float4*)(point_emb + i + 4);
    uint4 st;
    st.x = pkbf(v0.x, v0.y);
    st.y = pkbf(v0.z, v0.w);
    st.z = pkbf(v1.x, v1.y);
    st.w = pkbf(v1.z, v1.w);
    *(uint4*)((unsigned short*)peT + i) = st;
  } else if (b < 3072) {
    // ---- img transpose + fused pos-add ----
    int bb = b - 2048;                 // [0,1024): x=bb&3, y=(bb>>2)&63, z=bb>>8
    int x = bb & 3, y = (bb >> 2) & 63, z = bb >> 8;
    long zofs = (long)z * (256L * 4096L);
    const float* inz = img_emb + zofs;
    unsigned short* o1 = (unsigned short*)imgT + zofs;
    unsigned short* o2 = (unsigned short*)imgPosT + zofs;
    int i0 = x * 64, j0 = y * 64;
    int l = tid & 63, ty = tid >> 6;
    int i = i0 + l;
#pragma unroll
    for (int itr = 0; itr < 2; ++itr) {
      int j = j0 + ty * 16 + itr * 8;
      const float* p = inz + (long)i * 4096 + j;
      float4 v0 = *(const float4*)(p);
      float4 v1 = *(const float4*)(p + 4);
      float vv[8] = {v0.x, v0.y, v0.z, v0.w, v1.x, v1.y, v1.z, v1.w};
#pragma unroll
      for (int s = 0; s < 8; ++s) {
        float xx = vv[s];
        long o = (long)(j + s) * 256 + i;
        o1[o] = f2bf(xx);
        o2[o] = f2bf(xx + pos[o]);     // pos[(j+s)*256+i]
      }
    }
  } else if (b < 3264) {
    // ---- Wq/Wk/Wv transposes: 12 z-slices of 256x256 ----
    int bb = b - 3072;                 // [0,192): x=bb&3, y=(bb>>2)&3, z=bb>>4
    int x = bb & 3, y = (bb >> 2) & 3, z = bb >> 4;   // z in [0,12)
    const float* inz = (z < 4 ? Wq : (z < 8 ? Wk : Wv)) + (long)(z & 3) * 65536;
    unsigned short* oz = (unsigned short*)WqT + (long)z * 65536;
    transp64(inz, oz, 256, 256, x * 64, y * 64, tid);
  } else {
    // ---- Wo transpose: 1024x256 ----
    int bb = b - 3264;                 // [0,64): x=bb&15, y=bb>>4
    int x = bb & 15, y = bb >> 4;
    transp64(Wo, (unsigned short*)WoT, 1024, 256, x * 64, y * 64, tid);
  }
}

// ---------------------------------------------------------------------------
// QKV GEMM (pure bf16, compile-time shape M=4096 N=256 K=256, Hq=4):
//   C[z] = bf16((A[z/4] @ Bt[z%4]^T + bias[z%4]) * scale)
// A bf16 [B][4096][256]; Bt bf16 [4][256][256]. transC: store C^T vectorized.
// block 256, tile 128x64, grid (32, 4, 16).
// ---------------------------------------------------------------------------
__global__ __launch_bounds__(256) void gemm_qkv(
    const short* __restrict__ A, const short* __restrict__ Bt,
    const float* __restrict__ bias, short* __restrict__ Co,
    float scale, int transC)
{
  int z = blockIdx.z;
  const short* Az = A + (long)(z >> 2) * 1048576;
  const short* Btz = Bt + (long)(z & 3) * 65536;
  const float* biasz = bias + (long)(z & 3) * 256;
  short* Cz = Co + (long)z * 1048576;

  int tid = threadIdx.x;
  int w = tid >> 6, lane = tid & 63;
  int half = lane >> 5, ln = lane & 31;
  int wm = w & 1, wn = w >> 1;
  int row0 = blockIdx.x * 128 + wm * 64;
  int col0 = blockIdx.y * 64 + wn * 32;

  f16v acc0, acc1;
#pragma unroll
  for (int i = 0; i < 16; ++i) { acc0[i] = 0.f; acc1[i] = 0.f; }

  const short* ap0 = Az + (long)(row0 + ln) * 256 + half * 8;
  const short* ap1 = Az + (long)(row0 + 32 + ln) * 256 + half * 8;
  const short* bp  = Btz + (long)(col0 + ln) * 256 + half * 8;

#pragma unroll
  for (int kt = 0; kt < 16; ++kt) {
    bfrag a0 = *(const bfrag*)(ap0 + kt * 16);
    bfrag a1 = *(const bfrag*)(ap1 + kt * 16);
    bfrag bb = *(const bfrag*)(bp + kt * 16);
    acc0 = __builtin_amdgcn_mfma_f32_32x32x16_bf16(a0, bb, acc0, 0, 0, 0);
    acc1 = __builtin_amdgcn_mfma_f32_32x32x16_bf16(a1, bb, acc1, 0, 0, 0);
  }

  int col = col0 + ln;
  float bv = biasz[col];
  if (transC) {
#pragma unroll
    for (int t = 0; t < 2; ++t) {
      int rbase = row0 + t * 32;
#pragma unroll
      for (int g = 0; g < 4; ++g) {
        float v0 = ((t ? acc1[4*g+0] : acc0[4*g+0]) + bv) * scale;
        float v1 = ((t ? acc1[4*g+1] : acc0[4*g+1]) + bv) * scale;
        float v2 = ((t ? acc1[4*g+2] : acc0[4*g+2]) + bv) * scale;
        float v3 = ((t ? acc1[4*g+3] : acc0[4*g+3]) + bv) * scale;
        uint2 st;
        st.x = pkbf(v0, v1);
        st.y = pkbf(v2, v3);
        *(uint2*)&((unsigned short*)Cz)[(long)col * 4096 + rbase + 8 * g + 4 * half] = st;
      }
    }
  } else {
#pragma unroll
    for (int t = 0; t < 2; ++t) {
      int rbase = row0 + t * 32;
#pragma unroll
      for (int r = 0; r < 16; ++r) {
        float av = t ? acc1[r] : acc0[r];
        int rr = rbase + (r & 3) + 8 * (r >> 2) + 4 * half;
        ((unsigned short*)Cz)[(long)rr * 256 + col] = f2bf((av + bv) * scale);
      }
    }
  }
}

// ---------------------------------------------------------------------------
// Output projection (compile-time shape M=16384 N=256 K=1024):
// emb[r][col] = att(head-major bf16) @ WoT^T + bo + resid, fp32 output.
// A: [B][H][4096][256] bf16 (r=b*4096+n, k=h*256+e). grid (128,4,1), block 256.
// ---------------------------------------------------------------------------
__global__ __launch_bounds__(256) void gemm_out(
    const short* __restrict__ A, const short* __restrict__ Bt,
    const float* __restrict__ bias, float* __restrict__ Co,
    const float* __restrict__ resid)
{
  int tid = threadIdx.x;
  int w = tid >> 6, lane = tid & 63;
  int half = lane >> 5, ln = lane & 31;
  int wm = w & 1, wn = w >> 1;
  int row0 = blockIdx.x * 128 + wm * 64;
  int col0 = blockIdx.y * 64 + wn * 32;

  f16v acc0, acc1;
#pragma unroll
  for (int i = 0; i < 16; ++i) { acc0[i] = 0.f; acc1[i] = 0.f; }

  int r0 = row0 + ln, r1 = row0 + 32 + ln;
  long a0base = (long)(r0 >> 12) * 4194304 + (long)(r0 & 4095) * 256 + half * 8;
  long a1base = (long)(r1 >> 12) * 4194304 + (long)(r1 & 4095) * 256 + half * 8;
  const short* bp = Bt + (long)(col0 + ln) * 1024 + half * 8;

  for (int kh = 0; kh < 4; ++kh) {          // head-major K blocks
    const short* a0p = A + a0base + (long)kh * 1048576;
    const short* a1p = A + a1base + (long)kh * 1048576;
    const short* bkp = bp + kh * 256;
#pragma unroll
    for (int kt = 0; kt < 16; ++kt) {
      bfrag a0 = *(const bfrag*)(a0p + kt * 16);
      bfrag a1 = *(const bfrag*)(a1p + kt * 16);
      bfrag bb = *(const bfrag*)(bkp + kt * 16);
      acc0 = __builtin_amdgcn_mfma_f32_32x32x16_bf16(a0, bb, acc0, 0, 0, 0);
      acc1 = __builtin_amdgcn_mfma_f32_32x32x16_bf16(a1, bb, acc1, 0, 0, 0);
    }
  }

  int col = col0 + ln;
  float bv = bias[col];
#pragma unroll
  for (int t = 0; t < 2; ++t) {
    int rbase = row0 + t * 32;
#pragma unroll
    for (int r = 0; r < 16; ++r) {
      float av = t ? acc1[r] : acc0[r];
      int rr = rbase + (r & 3) + 8 * (r >> 2) + 4 * half;
      Co[(long)rr * 256 + col] = av + bv + resid[(long)rr * 256 + col];
    }
  }
}

// ---------------------------------------------------------------------------
// Flash attention — EXACT ROUND-4 KERNEL (302.6 µs, best measured).
// 8 waves / 512 thr / 1 block per CU, head-major XCD swizzle, 64KB LDS dbuf,
// global_load_lds DMA staging with pre-swizzled global source, V one tile
// behind K, static-max base-2 softmax.
// Closed experiments: setprio (r1, -25µs), 4-wave 2-block/CU (r3 reg-blowup;
// r5 co-resident but L2-thrash + write-amp, -104µs). Keep 1 block/CU.
// ---------------------------------------------------------------------------
__global__ __launch_bounds__(512, 2) void attn_kernel(
    const short* __restrict__ Qg, const short* __restrict__ Kg,
    const short* __restrict__ Vtg, short* __restrict__ attc)
{
  __shared__ char smem[65536];   // buf b at b*32768: [K 16KB | V 16KB]
  int bx = blockIdx.x;
  int bh = bx & 15, qg = bx >> 4;          // head-major XCD swizzle (load-bearing)
  int tid = threadIdx.x;
  int w = tid >> 6, lane = tid & 63;
  int half = lane >> 5, ln = lane & 31;
  int q0 = qg * 256 + w * 32;

  // Q fragments (B-operand): lane ln holds q-row q0+ln, k = 16kt + 8half + j.
  bfrag qf[16];
  {
    const short* qrow = Qg + ((long)bh * 4096 + q0 + ln) * 256 + half * 8;
#pragma unroll
    for (int kt = 0; kt < 16; ++kt) qf[kt] = *(const bfrag*)(qrow + kt * 16);
  }

  // MFMA-read LDS byte offsets
  int koff[4], voff[2];
#pragma unroll
  for (int m = 0; m < 4; ++m) koff[m] = ((ln ^ (2 * m + half)) * 16) + half * 512;
#pragma unroll
  for (int kp = 0; kp < 2; ++kp) {
    int ck = 2 * kp + half;
    voff[kp] = 16384 + ck * 4096 + ((ln ^ (ck << 1)) * 16);
  }

  // DMA source offsets: wave w stages LDS 1KB chunks wc = 2w, 2w+1 of each
  // tile (K half and V half). Inverse swizzle on the global side.
  int w2 = w * 2;
  int kgl0, kgl1, vgl0, vgl1;
  {
    int c0 = w2 * 2 + half;
    kgl0 = (ln ^ (c0 & 7)) * 512 + c0 * 16;
    int c1 = (w2 + 1) * 2 + half;
    kgl1 = (ln ^ (c1 & 7)) * 512 + c1 * 16;
    int ck0 = w2 >> 2;
    int e0 = ((w2 & 3) * 64 + lane) ^ (ck0 << 1);
    vgl0 = e0 * 8192 + ck0 * 16;
    int ck1 = (w2 + 1) >> 2;
    int e1 = (((w2 + 1) & 3) * 64 + lane) ^ (ck1 << 1);
    vgl1 = e1 * 8192 + ck1 * 16;
  }
  const char* kgp = (const char*)Kg + (long)bh * 2097152;   // += 16384 per tile
  const char* vgp = (const char*)Vtg + (long)bh * 2097152;  // += 64 per tile

  f16v O[8];
#pragma unroll
  for (int t = 0; t < 8; ++t)
#pragma unroll
    for (int r = 0; r < 16; ++r) O[t][r] = 0.f;

  float l_run = 0.f;
  union { bfrag f; unsigned u[4]; } bb[2];

  // prologue: DMA K_0 into buf0
  dma16(kgp + kgl0, smem + w2 * 1024);
  dma16(kgp + kgl1, smem + (w2 + 1) * 1024);
  kgp += 16384;

  // iter 0: S(K_0) from buf0, DMA K_1 + V_0 into buf1 (no V-MFMA yet)
  __syncthreads();
  dma16(kgp + kgl0, smem + 32768 + w2 * 1024);
  dma16(kgp + kgl1, smem + 32768 + (w2 + 1) * 1024);
  kgp += 16384;
  dma16(vgp + vgl0, smem + 32768 + 16384 + w2 * 1024);
  dma16(vgp + vgl1, smem + 32768 + 16384 + (w2 + 1) * 1024);
  vgp += 64;
  {
    f16v S;
#pragma unroll
    for (int r = 0; r < 16; ++r) S[r] = 0.f;
#pragma unroll
    for (int kt = 0; kt < 16; ++kt) {
      bfrag a = *(const bfrag*)(smem + koff[kt & 3] + kt * 1024);
      S = __builtin_amdgcn_mfma_f32_32x32x16_bf16(a, qf[kt], S, 0, 0, 0);
    }
    float ss = 0.f;
#pragma unroll
    for (int r = 0; r < 16; ++r) { float e = exp2f(S[r] - 8.f); S[r] = e; ss += e; }
    l_run += ss;
#pragma unroll
    for (int kp = 0; kp < 2; ++kp) {
      unsigned pk0 = pk2f(S[8 * kp + 0], S[8 * kp + 1]);
      unsigned pk1 = pk2f(S[8 * kp + 2], S[8 * kp + 3]);
      unsigned pk2 = pk2f(S[8 * kp + 4], S[8 * kp + 5]);
      unsigned pk3 = pk2f(S[8 * kp + 6], S[8 * kp + 7]);
      unsigned o0 = (unsigned)__shfl_xor((int)pk0, 32);
      unsigned o1 = (unsigned)__shfl_xor((int)pk1, 32);
      unsigned o2 = (unsigned)__shfl_xor((int)pk2, 32);
      unsigned o3 = (unsigned)__shfl_xor((int)pk3, 32);
      bb[kp].u[0] = half ? o2 : pk0;
      bb[kp].u[1] = half ? o3 : pk1;
      bb[kp].u[2] = half ? pk2 : o0;
      bb[kp].u[3] = half ? pk3 : o1;
    }
  }

// one pipelined iteration with compile-time buffer parity.
// reads K_t (buf BUF) + V_{t-1} (buf BUF); DMAs K_{t+1}+V_t into buf BUF^1.
// the barrier at the top drains last iter's DMAs (implicit vmcnt(0)).
#define ATTN_ITER(BUF, KLOAD)                                                  \
  {                                                                            \
    __syncthreads();                                                           \
    if (KLOAD) {                                                               \
      dma16(kgp + kgl0, smem + ((BUF) ^ 1) * 32768 + w2 * 1024);               \
      dma16(kgp + kgl1, smem + ((BUF) ^ 1) * 32768 + (w2 + 1) * 1024);         \
      kgp += 16384;                                                            \
    }                                                                          \
    dma16(vgp + vgl0, smem + ((BUF) ^ 1) * 32768 + 16384 + w2 * 1024);         \
    dma16(vgp + vgl1, smem + ((BUF) ^ 1) * 32768 + 16384 + (w2 + 1) * 1024);   \
    vgp += 64;                                                                 \
    f16v S;                                                                    \
    _Pragma("unroll")                                                          \
    for (int r = 0; r < 16; ++r) S[r] = 0.f;                                   \
    _Pragma("unroll")                                                          \
    for (int kt = 0; kt < 16; ++kt) {                                          \
      bfrag a = *(const bfrag*)(smem + koff[kt & 3] + ((BUF)*32768 + kt*1024));\
      S = __builtin_amdgcn_mfma_f32_32x32x16_bf16(a, qf[kt], S, 0, 0, 0);      \
      bfrag va = *(const bfrag*)(smem + voff[kt >> 3] +                        \
                                 ((BUF)*32768 + (kt & 7) * 512));              \
      O[kt & 7] = __builtin_amdgcn_mfma_f32_32x32x16_bf16(va, bb[kt >> 3].f,   \
                                                          O[kt & 7], 0, 0, 0); \
    }                                                                          \
    float ss = 0.f;                                                            \
    _Pragma("unroll")                                                          \
    for (int r = 0; r < 16; ++r) { float e = exp2f(S[r] - 8.f); S[r] = e; ss += e; } \
    l_run += ss;                                                               \
    _Pragma("unroll")                                                          \
    for (int kp = 0; kp < 2; ++kp) {                                           \
      unsigned pk0 = pk2f(S[8 * kp + 0], S[8 * kp + 1]);                       \
      unsigned pk1 = pk2f(S[8 * kp + 2], S[8 * kp + 3]);                       \
      unsigned pk2 = pk2f(S[8 * kp + 4], S[8 * kp + 5]);                       \
      unsigned pk3 = pk2f(S[8 * kp + 6], S[8 * kp + 7]);                       \
      unsigned o0 = (unsigned)__shfl_xor((int)pk0, 32);                        \
      unsigned o1 = (unsigned)__shfl_xor((int)pk1, 32);                        \
      unsigned o2 = (unsigned)__shfl_xor((int)pk2, 32);                        \
      unsigned o3 = (unsigned)__shfl_xor((int)pk3, 32);                        \
      bb[kp].u[0] = half ? o2 : pk0;                                           \
      bb[kp].u[1] = half ? o3 : pk1;                                           \
      bb[kp].u[2] = half ? pk2 : o0;                                           \
      bb[kp].u[3] = half ? pk3 : o1;                                           \
    }                                                                          \
  }

  // t = 1..126 as 63 static-parity pairs, then t = 127.
  for (int tp = 0; tp < 63; ++tp) {
    ATTN_ITER(1, 1)     // odd t
    ATTN_ITER(0, 1)     // even t
  }
  ATTN_ITER(1, 0)       // t = 127: no K prefetch; V_127 DMA'd into buf0
#undef ATTN_ITER

  // epilogue: V-MFMA for tile 127 (buf0 V half)
  __syncthreads();
#pragma unroll
  for (int kp = 0; kp < 2; ++kp) {
#pragma unroll
    for (int mt = 0; mt < 8; ++mt) {
      bfrag va = *(const bfrag*)(smem + voff[kp] + mt * 512);
      O[mt] = __builtin_amdgcn_mfma_f32_32x32x16_bf16(va, bb[kp].f, O[mt], 0, 0, 0);
    }
  }

  // attc[bh][q][e] = O^T[e][q]/l.  l = own-half + partner-half.
  l_run += __shfl_xor(l_run, 32);
  float rl = 1.0f / l_run;
  short* orow = attc + ((long)bh * 4096 + q0 + ln) * 256;
#pragma unroll
  for (int mt = 0; mt < 8; ++mt) {
#pragma unroll
    for (int g = 0; g < 4; ++g) {
      uint2 st;
      st.x = pkbf(O[mt][4 * g + 0] * rl, O[mt][4 * g + 1] * rl);
      st.y = pkbf(O[mt][4 * g + 2] * rl, O[mt][4 * g + 3] * rl);
      *(uint2*)(orow + mt * 32 + 8 * g + 4 * half) = st;
    }
  }
}

// ---------------------------------------------------------------------------
// FFN head (all fp32): 16 rows per 256-thr block, 4 rows per wave.
// x/h stored transposed in LDS ([k][4rows]) so one broadcast ds_read_b128
// feeds 4 rows; W1/W2 loads amortized 4x. Per-wave buffers -> no barriers.
// ---------------------------------------------------------------------------
__global__ __launch_bounds__(256) void ffn_kernel(
    const float* __restrict__ emb,
    const float* __restrict__ W1, const float* __restrict__ b1,
    const float* __restrict__ g1, const float* __restrict__ be1,
    const float* __restrict__ W2, const float* __restrict__ b2,
    const float* __restrict__ g2, const float* __restrict__ be2,
    const float* __restrict__ W3, const float* __restrict__ b3,
    float* __restrict__ act)
{
  __shared__ float xs[4][256][4];   // [wave][k][row]  16KB
  __shared__ float hs[4][128][4];   // [wave][k][row]   8KB
  int w = threadIdx.x >> 6, l = threadIdx.x & 63;
  int row0 = blockIdx.x * 16 + w * 4;
  const float* x = emb + (long)row0 * 256;

  // load 4 rows, store transposed: lane l owns positions 4l..4l+3
  {
    float xv[4][4];   // [i][row]
#pragma unroll
    for (int rr = 0; rr < 4; ++rr) {
      float4 t = *(const float4*)(x + rr * 256 + 4 * l);
      xv[0][rr] = t.x; xv[1][rr] = t.y; xv[2][rr] = t.z; xv[3][rr] = t.w;
    }
#pragma unroll
    for (int i = 0; i < 4; ++i) {
      float4 st = make_float4(xv[i][0], xv[i][1], xv[i][2], xv[i][3]);
      *(float4*)&xs[w][4 * l + i][0] = st;
    }
  }

  // layer 1: 128 outputs, lane l owns outputs 2l, 2l+1, 4 rows each
  float a0[4], a1[4];
  {
    float bb0 = b1[2 * l], bb1 = b1[2 * l + 1];
#pragma unroll
    for (int rr = 0; rr < 4; ++rr) { a0[rr] = bb0; a1[rr] = bb1; }
  }
  for (int k = 0; k < 256; ++k) {
    float w0 = W1[k * 128 + 2 * l], w1 = W1[k * 128 + 2 * l + 1];
    float4 xv = *(const float4*)&xs[w][k][0];
    a0[0] += xv.x * w0; a1[0] += xv.x * w1;
    a0[1] += xv.y * w0; a1[1] += xv.y * w1;
    a0[2] += xv.z * w0; a1[2] += xv.z * w1;
    a0[3] += xv.w * w0; a1[3] += xv.w * w1;
  }
  {
    float gg0 = g1[2 * l], gg1 = g1[2 * l + 1];
    float ee0 = be1[2 * l], ee1 = be1[2 * l + 1];
    float n0v[4], n1v[4];
#pragma unroll
    for (int rr = 0; rr < 4; ++rr) {
      float u0 = fmaxf(a0[rr], 0.f), u1 = fmaxf(a1[rr], 0.f);
      float s1 = wred(u0 + u1);
      float s2 = wred(u0 * u0 + u1 * u1);
      float mu = s1 * (1.f / 128.f);
      float var = fmaxf(s2 * (1.f / 128.f) - mu * mu, 0.f);
      float rs = rsqrtf(var + 1e-5f);
      n0v[rr] = (u0 - mu) * rs * gg0 + ee0;
      n1v[rr] = (u1 - mu) * rs * gg1 + ee1;
    }
    *(float4*)&hs[w][2 * l][0]     = make_float4(n0v[0], n0v[1], n0v[2], n0v[3]);
    *(float4*)&hs[w][2 * l + 1][0] = make_float4(n1v[0], n1v[1], n1v[2], n1v[3]);
  }

  // layer 2: 64 outputs, lane l owns output l, 4 rows
  float c0[4];
  {
    float bb2 = b2[l];
#pragma unroll
    for (int rr = 0; rr < 4; ++rr) c0[rr] = bb2;
  }
  for (int k = 0; k < 128; ++k) {
    float w2 = W2[k * 64 + l];
    float4 hv = *(const float4*)&hs[w][k][0];
    c0[0] += hv.x * w2;
    c0[1] += hv.y * w2;
    c0[2] += hv.z * w2;
    c0[3] += hv.w * w2;
  }
  {
    float gg2 = g2[l], ee2 = be2[l], w3 = W3[l], bb3 = b3[0];
#pragma unroll
    for (int rr = 0; rr < 4; ++rr) {
      float u = fmaxf(c0[rr], 0.f);
      float t1 = wred(u);
      float t2 = wred(u * u);
      float mu2 = t1 * (1.f / 64.f);
      float var2 = fmaxf(t2 * (1.f / 64.f) - mu2 * mu2, 0.f);
      float rs2 = rsqrtf(var2 + 1e-5f);
      float n2 = (u - mu2) * rs2 * gg2 + ee2;
      float tt = wred(n2 * w3);
      if (l == 0) {
        float r = tt + bb3;
        act[row0 + rr] = 1.f / (1.f + __expf(-r));
      }
    }
  }
}

// ---------------------------------------------------------------------------
extern "C" void kernel_launch(void* const* d_in, const int* in_sizes, int n_in,
                              void* d_out, int out_size, void* d_ws, size_t ws_size,
                              hipStream_t stream)
{
  const float* img_emb   = (const float*)d_in[0];
  const float* point_emb = (const float*)d_in[1];
  const float* Wq = (const float*)d_in[2];
  const float* bq = (const float*)d_in[3];
  const float* Wk = (const float*)d_in[4];
  const float* bk = (const float*)d_in[5];
  const float* Wv = (const float*)d_in[6];
  const float* bv = (const float*)d_in[7];
  const float* Wo = (const float*)d_in[8];
  const float* bo = (const float*)d_in[9];
  const float* pos = (const float*)d_in[10];
  const float* W1 = (const float*)d_in[11];
  const float* b1 = (const float*)d_in[12];
  const float* g1 = (const float*)d_in[13];
  const float* be1 = (const float*)d_in[14];
  const float* W2 = (const float*)d_in[15];
  const float* b2 = (const float*)d_in[16];
  const float* g2 = (const float*)d_in[17];
  const float* be2 = (const float*)d_in[18];
  const float* W3 = (const float*)d_in[19];
  const float* b3 = (const float*)d_in[20];

  // ws layout (111.1 MB), all internal tensors bf16.
  // peT/imgT live INSIDE the VtB region: both are dead before the V-gemm
  // (the only writer of VtB) runs — stream order guarantees safety.
  // (Do NOT merge the three qkv GEMM launches: that ordering is load-bearing.)
  char* ws = (char*)d_ws;
  short* Qb      = (short*)(ws + 0);            // 33.55 MB [BH][4096][256]; attn out in-place
  short* Kb      = (short*)(ws + 33554432);     // 33.55 MB [BH][4096][256]
  short* VtB     = (short*)(ws + 67108864);     // 33.55 MB [BH][256][4096]
  short* peT     = (short*)(ws + 67108864);     //  8.39 MB [B][4096][256]  (dead after Q-gemm)
  short* imgT    = (short*)(ws + 75497472);     //  8.39 MB [B][4096][256]  (dead after K-gemm)
  short* imgPosT = (short*)(ws + 100663296);    //  8.39 MB [B][4096][256]
  short* WoT     = (short*)(ws + 109051904);    //  0.52 MB [256][1024]
  short* WqT     = (short*)(ws + 109576192);    //  0.13 MB [H][256][256]  (WkT,WvT follow)
  short* WkT     = (short*)(ws + 110100480);
  short* WvT     = (short*)(ws + 110624768);
  (void)WkT; (void)WvT;

  float* act_out = (float*)d_out;            // [B*N]
  float* emb_out = (float*)d_out + 16384;    // [B*N][256]

  const float qscale = 0.0901684400555602f;  // log2(e)/sqrt(256)

  // fused prep: all weight transposes + img transpose/pos-add + point_emb cast
  prep_kernel<<<3328, 256, 0, stream>>>(point_emb, peT, img_emb, pos,
                                        imgT, imgPosT, Wq, Wk, Wv, WqT, Wo, WoT);

  // Q = (point_emb @ WqT + bq) * qscale      (reads peT — before VtB written)
  gemm_qkv<<<dim3(32, 4, 16), 256, 0, stream>>>(peT, WqT, bq, Qb, qscale, 0);
  // K = img @ WkT + bk                       (reads imgT — before VtB written)
  gemm_qkv<<<dim3(32, 4, 16), 256, 0, stream>>>(imgT, WqT + 262144, bk, Kb, 1.0f, 0);
  // V^T = ((img + pos) @ WvT + bv)^T         (reads imgPosT, writes VtB)
  gemm_qkv<<<dim3(32, 4, 16), 256, 0, stream>>>(imgPosT, WqT + 524288, bv, VtB, 1.0f, 1);

  // attention: reads Qb/Kb/VtB, writes att in-place over Qb ([BH][N][256])
  attn_kernel<<<256, 512, 0, stream>>>(Qb, Kb, VtB, Qb);

  // emb = att @ Wo + bo + point_emb  (fp32 out)
  gemm_out<<<dim3(128, 4, 1), 256, 0, stream>>>(Qb, WoT, bo, emb_out, point_emb);

  // FFN head -> act (fp32)
  ffn_kernel<<<1024, 256, 0, stream>>>(emb_out, W1, b1, g1, be1, W2, b2, g2, be2,
                                       W3, b3, act_out);
}

// Round 7
// 627.862 us; speedup vs baseline: 1.1461x; 1.0164x over previous
//
#include <hip/hip_runtime.h>

typedef __attribute__((ext_vector_type(8))) short bfrag;          // 8 bf16 (4 VGPRs)
typedef __attribute__((ext_vector_type(8))) unsigned short us8;
typedef __attribute__((ext_vector_type(16))) float f16v;          // 32x32 MFMA acc

__device__ __forceinline__ unsigned short f2bf(float f) {
  union { float f; unsigned u; } v; v.f = f;
  unsigned u = v.u;
  return (unsigned short)((u + 0x7fffu + ((u >> 16) & 1u)) >> 16);  // RNE
}
__device__ __forceinline__ unsigned pkbf(float a, float b) {
  return (unsigned)f2bf(a) | ((unsigned)f2bf(b) << 16);
}
__device__ __forceinline__ float wred(float v) {
#pragma unroll
  for (int m = 32; m >= 1; m >>= 1) v += __shfl_xor(v, m, 64);
  return v;
}
// async global->LDS DMA, 16B per lane (global source may be per-lane scattered;
// LDS dest is wave-uniform base + lane*16).
__device__ __forceinline__ void dma16(const void* g, void* l) {
  __builtin_amdgcn_global_load_lds(
      (const __attribute__((address_space(1))) void*)g,
      (__attribute__((address_space(3))) void*)l, 16, 0, 0);
}

// ---------------------------------------------------------------------------
// Fused prep kernel: point_emb cast + img transpose/pos-add + W transposes.
// Flattened 1-D grid, block 256:
//   [0, 2048)      : point_emb fp32->bf16 cast (peT)
//   [2048, 3072)   : img transpose + fused pos-add (imgT, imgPosT)
//   [3072, 3264)   : Wq/Wk/Wv 256x256 transposes (12 z-slices)
//   [3264, 3328)   : Wo 1024x256 transpose
// ---------------------------------------------------------------------------
__device__ __forceinline__ void transp64(
    const float* __restrict__ inz, unsigned short* __restrict__ oz,
    int R, int Cc, int i0, int j0, int tid)
{
  int l = tid & 63, ty = tid >> 6;
  int i = i0 + l;
#pragma unroll
  for (int itr = 0; itr < 2; ++itr) {
    int j = j0 + ty * 16 + itr * 8;
    const float* p = inz + (long)i * Cc + j;
    float4 v0 = *(const float4*)(p);
    float4 v1 = *(const float4*)(p + 4);
    float vv[8] = {v0.x, v0.y, v0.z, v0.w, v1.x, v1.y, v1.z, v1.w};
#pragma unroll
    for (int s = 0; s < 8; ++s) oz[(long)(j + s) * R + i] = f2bf(vv[s]);
  }
}

__global__ __launch_bounds__(256) void prep_kernel(
    const float* __restrict__ point_emb, short* __restrict__ peT,
    const float* __restrict__ img_emb, const float* __restrict__ pos,
    short* __restrict__ imgT, short* __restrict__ imgPosT,
    const float* __restrict__ Wq, const float* __restrict__ Wk,
    const float* __restrict__ Wv, short* __restrict__ WqT,
    const float* __restrict__ Wo, short* __restrict__ WoT)
{
  int b = blockIdx.x;
  int tid = threadIdx.x;

  if (b < 2048) {
    // ---- point_emb cast: 8 elems/thread ----
    long i = ((long)b * 256 + tid) * 8;
    float4 v0 = *(const float4*)(point_emb + i);
    float4 v1 = *(const float4*)(point_emb + i + 4);
    uint4 st;
    st.x = pkbf(v0.x, v0.y);
    st.y = pkbf(v0.z, v0.w);
    st.z = pkbf(v1.x, v1.y);
    st.w = pkbf(v1.z, v1.w);
    *(uint4*)((unsigned short*)peT + i) = st;
  } else if (b < 3072) {
    // ---- img transpose + fused pos-add ----
    int bb = b - 2048;                 // [0,1024): x=bb&3, y=(bb>>2)&63, z=bb>>8
    int x = bb & 3, y = (bb >> 2) & 63, z = bb >> 8;
    long zofs = (long)z * (256L * 4096L);
    const float* inz = img_emb + zofs;
    unsigned short* o1 = (unsigned short*)imgT + zofs;
    unsigned short* o2 = (unsigned short*)imgPosT + zofs;
    int i0 = x * 64, j0 = y * 64;
    int l = tid & 63, ty = tid >> 6;
    int i = i0 + l;
#pragma unroll
    for (int itr = 0; itr < 2; ++itr) {
      int j = j0 + ty * 16 + itr * 8;
      const float* p = inz + (long)i * 4096 + j;
      float4 v0 = *(const float4*)(p);
      float4 v1 = *(const float4*)(p + 4);
      float vv[8] = {v0.x, v0.y, v0.z, v0.w, v1.x, v1.y, v1.z, v1.w};
#pragma unroll
      for (int s = 0; s < 8; ++s) {
        float xx = vv[s];
        long o = (long)(j + s) * 256 + i;
        o1[o] = f2bf(xx);
        o2[o] = f2bf(xx + pos[o]);     // pos[(j+s)*256+i]
      }
    }
  } else if (b < 3264) {
    // ---- Wq/Wk/Wv transposes: 12 z-slices of 256x256 ----
    int bb = b - 3072;                 // [0,192): x=bb&3, y=(bb>>2)&3, z=bb>>4
    int x = bb & 3, y = (bb >> 2) & 3, z = bb >> 4;   // z in [0,12)
    const float* inz = (z < 4 ? Wq : (z < 8 ? Wk : Wv)) + (long)(z & 3) * 65536;
    unsigned short* oz = (unsigned short*)WqT + (long)z * 65536;
    transp64(inz, oz, 256, 256, x * 64, y * 64, tid);
  } else {
    // ---- Wo transpose: 1024x256 ----
    int bb = b - 3264;                 // [0,64): x=bb&15, y=bb>>4
    int x = bb & 15, y = bb >> 4;
    transp64(Wo, (unsigned short*)WoT, 1024, 256, x * 64, y * 64, tid);
  }
}

// ---------------------------------------------------------------------------
// QKV GEMM (pure bf16, compile-time shape M=4096 N=256 K=256, Hq=4):
//   C[z] = bf16((A[z/4] @ Bt[z%4]^T + bias[z%4]) * scale)
// A bf16 [B][4096][256]; Bt bf16 [4][256][256]. transC: store C^T vectorized.
// block 256, tile 128x64, grid (32, 4, 16).
// ---------------------------------------------------------------------------
__global__ __launch_bounds__(256) void gemm_qkv(
    const short* __restrict__ A, const short* __restrict__ Bt,
    const float* __restrict__ bias, short* __restrict__ Co,
    float scale, int transC)
{
  int z = blockIdx.z;
  const short* Az = A + (long)(z >> 2) * 1048576;
  const short* Btz = Bt + (long)(z & 3) * 65536;
  const float* biasz = bias + (long)(z & 3) * 256;
  short* Cz = Co + (long)z * 1048576;

  int tid = threadIdx.x;
  int w = tid >> 6, lane = tid & 63;
  int half = lane >> 5, ln = lane & 31;
  int wm = w & 1, wn = w >> 1;
  int row0 = blockIdx.x * 128 + wm * 64;
  int col0 = blockIdx.y * 64 + wn * 32;

  f16v acc0, acc1;
#pragma unroll
  for (int i = 0; i < 16; ++i) { acc0[i] = 0.f; acc1[i] = 0.f; }

  const short* ap0 = Az + (long)(row0 + ln) * 256 + half * 8;
  const short* ap1 = Az + (long)(row0 + 32 + ln) * 256 + half * 8;
  const short* bp  = Btz + (long)(col0 + ln) * 256 + half * 8;

#pragma unroll
  for (int kt = 0; kt < 16; ++kt) {
    bfrag a0 = *(const bfrag*)(ap0 + kt * 16);
    bfrag a1 = *(const bfrag*)(ap1 + kt * 16);
    bfrag bb = *(const bfrag*)(bp + kt * 16);
    acc0 = __builtin_amdgcn_mfma_f32_32x32x16_bf16(a0, bb, acc0, 0, 0, 0);
    acc1 = __builtin_amdgcn_mfma_f32_32x32x16_bf16(a1, bb, acc1, 0, 0, 0);
  }

  int col = col0 + ln;
  float bv = biasz[col];
  if (transC) {
#pragma unroll
    for (int t = 0; t < 2; ++t) {
      int rbase = row0 + t * 32;
#pragma unroll
      for (int g = 0; g < 4; ++g) {
        float v0 = ((t ? acc1[4*g+0] : acc0[4*g+0]) + bv) * scale;
        float v1 = ((t ? acc1[4*g+1] : acc0[4*g+1]) + bv) * scale;
        float v2 = ((t ? acc1[4*g+2] : acc0[4*g+2]) + bv) * scale;
        float v3 = ((t ? acc1[4*g+3] : acc0[4*g+3]) + bv) * scale;
        uint2 st;
        st.x = pkbf(v0, v1);
        st.y = pkbf(v2, v3);
        *(uint2*)&((unsigned short*)Cz)[(long)col * 4096 + rbase + 8 * g + 4 * half] = st;
      }
    }
  } else {
#pragma unroll
    for (int t = 0; t < 2; ++t) {
      int rbase = row0 + t * 32;
#pragma unroll
      for (int r = 0; r < 16; ++r) {
        float av = t ? acc1[r] : acc0[r];
        int rr = rbase + (r & 3) + 8 * (r >> 2) + 4 * half;
        ((unsigned short*)Cz)[(long)rr * 256 + col] = f2bf((av + bv) * scale);
      }
    }
  }
}

// ---------------------------------------------------------------------------
// Output projection (compile-time shape M=16384 N=256 K=1024):
// emb[r][col] = att(head-major bf16) @ WoT^T + bo + resid, fp32 output.
// A: [B][H][4096][256] bf16 (r=b*4096+n, k=h*256+e). grid (128,4,1), block 256.
// ---------------------------------------------------------------------------
__global__ __launch_bounds__(256) void gemm_out(
    const short* __restrict__ A, const short* __restrict__ Bt,
    const float* __restrict__ bias, float* __restrict__ Co,
    const float* __restrict__ resid)
{
  int tid = threadIdx.x;
  int w = tid >> 6, lane = tid & 63;
  int half = lane >> 5, ln = lane & 31;
  int wm = w & 1, wn = w >> 1;
  int row0 = blockIdx.x * 128 + wm * 64;
  int col0 = blockIdx.y * 64 + wn * 32;

  f16v acc0, acc1;
#pragma unroll
  for (int i = 0; i < 16; ++i) { acc0[i] = 0.f; acc1[i] = 0.f; }

  int r0 = row0 + ln, r1 = row0 + 32 + ln;
  long a0base = (long)(r0 >> 12) * 4194304 + (long)(r0 & 4095) * 256 + half * 8;
  long a1base = (long)(r1 >> 12) * 4194304 + (long)(r1 & 4095) * 256 + half * 8;
  const short* bp = Bt + (long)(col0 + ln) * 1024 + half * 8;

  for (int kh = 0; kh < 4; ++kh) {          // head-major K blocks
    const short* a0p = A + a0base + (long)kh * 1048576;
    const short* a1p = A + a1base + (long)kh * 1048576;
    const short* bkp = bp + kh * 256;
#pragma unroll
    for (int kt = 0; kt < 16; ++kt) {
      bfrag a0 = *(const bfrag*)(a0p + kt * 16);
      bfrag a1 = *(const bfrag*)(a1p + kt * 16);
      bfrag bb = *(const bfrag*)(bkp + kt * 16);
      acc0 = __builtin_amdgcn_mfma_f32_32x32x16_bf16(a0, bb, acc0, 0, 0, 0);
      acc1 = __builtin_amdgcn_mfma_f32_32x32x16_bf16(a1, bb, acc1, 0, 0, 0);
    }
  }

  int col = col0 + ln;
  float bv = bias[col];
#pragma unroll
  for (int t = 0; t < 2; ++t) {
    int rbase = row0 + t * 32;
#pragma unroll
    for (int r = 0; r < 16; ++r) {
      float av = t ? acc1[r] : acc0[r];
      int rr = rbase + (r & 3) + 8 * (r >> 2) + 4 * half;
      Co[(long)rr * 256 + col] = av + bv + resid[(long)rr * 256 + col];
    }
  }
}

// ---------------------------------------------------------------------------
// Flash attention — r4 structure (297.9 µs) + ROUND 7: T12 softmax pack.
// The P->bf16 B-fragment pack now uses v_cvt_pk_bf16_f32 (1 op vs ~5 int-ALU
// per pair) and v_permlane32_swap_b32 (VALU lane[i]<->lane[i+32] exchange;
// rows 2-3 of src0 swap with rows 0-1 of src1) instead of 4x ds_bpermute
// (__shfl_xor 32) + 16 cndmask — removes the LDS-pipe shuffles that compete
// with the 32 ds_read_b128/iter, and the divergent half? selects.
// Mapping verified: swap(pk0,pk2) -> {u[0],u[2]}, swap(pk1,pk3) -> {u[1],u[3]}.
// Closed: setprio (r1 -25µs), 4-wave 2-block/CU (r3 regs; r5 L2-thrash).
// ---------------------------------------------------------------------------
__global__ __launch_bounds__(512, 2) void attn_kernel(
    const short* __restrict__ Qg, const short* __restrict__ Kg,
    const short* __restrict__ Vtg, short* __restrict__ attc)
{
  __shared__ char smem[65536];   // buf b at b*32768: [K 16KB | V 16KB]
  int bx = blockIdx.x;
  int bh = bx & 15, qg = bx >> 4;          // head-major XCD swizzle (load-bearing)
  int tid = threadIdx.x;
  int w = tid >> 6, lane = tid & 63;
  int half = lane >> 5, ln = lane & 31;
  int q0 = qg * 256 + w * 32;

  // Q fragments (B-operand): lane ln holds q-row q0+ln, k = 16kt + 8half + j.
  bfrag qf[16];
  {
    const short* qrow = Qg + ((long)bh * 4096 + q0 + ln) * 256 + half * 8;
#pragma unroll
    for (int kt = 0; kt < 16; ++kt) qf[kt] = *(const bfrag*)(qrow + kt * 16);
  }

  // MFMA-read LDS byte offsets
  int koff[4], voff[2];
#pragma unroll
  for (int m = 0; m < 4; ++m) koff[m] = ((ln ^ (2 * m + half)) * 16) + half * 512;
#pragma unroll
  for (int kp = 0; kp < 2; ++kp) {
    int ck = 2 * kp + half;
    voff[kp] = 16384 + ck * 4096 + ((ln ^ (ck << 1)) * 16);
  }

  // DMA source offsets: wave w stages LDS 1KB chunks wc = 2w, 2w+1 of each
  // tile (K half and V half). Inverse swizzle on the global side.
  int w2 = w * 2;
  int kgl0, kgl1, vgl0, vgl1;
  {
    int c0 = w2 * 2 + half;
    kgl0 = (ln ^ (c0 & 7)) * 512 + c0 * 16;
    int c1 = (w2 + 1) * 2 + half;
    kgl1 = (ln ^ (c1 & 7)) * 512 + c1 * 16;
    int ck0 = w2 >> 2;
    int e0 = ((w2 & 3) * 64 + lane) ^ (ck0 << 1);
    vgl0 = e0 * 8192 + ck0 * 16;
    int ck1 = (w2 + 1) >> 2;
    int e1 = (((w2 + 1) & 3) * 64 + lane) ^ (ck1 << 1);
    vgl1 = e1 * 8192 + ck1 * 16;
  }
  const char* kgp = (const char*)Kg + (long)bh * 2097152;   // += 16384 per tile
  const char* vgp = (const char*)Vtg + (long)bh * 2097152;  // += 64 per tile

  f16v O[8];
#pragma unroll
  for (int t = 0; t < 8; ++t)
#pragma unroll
    for (int r = 0; r < 16; ++r) O[t][r] = 0.f;

  float l_run = 0.f;
  union { bfrag f; unsigned u[4]; } bb[2];

// softmax P-pack: S[8kp..8kp+7] (f32) -> bb[kp] (8 bf16, B-fragment layout).
// cvt_pk packs pairs; permlane32_swap exchanges hi-lanes(a) <-> lo-lanes(b).
#define PACK_BB(kp)                                                            \
  {                                                                            \
    unsigned q0_, q1_, q2_, q3_;                                               \
    asm("v_cvt_pk_bf16_f32 %0, %1, %2"                                         \
        : "=v"(q0_) : "v"(S[8*(kp)+0]), "v"(S[8*(kp)+1]));                     \
    asm("v_cvt_pk_bf16_f32 %0, %1, %2"                                         \
        : "=v"(q1_) : "v"(S[8*(kp)+2]), "v"(S[8*(kp)+3]));                     \
    asm("v_cvt_pk_bf16_f32 %0, %1, %2"                                         \
        : "=v"(q2_) : "v"(S[8*(kp)+4]), "v"(S[8*(kp)+5]));                     \
    asm("v_cvt_pk_bf16_f32 %0, %1, %2"                                         \
        : "=v"(q3_) : "v"(S[8*(kp)+6]), "v"(S[8*(kp)+7]));                     \
    asm("v_permlane32_swap_b32 %0, %1" : "+v"(q0_), "+v"(q2_));                \
    asm("v_permlane32_swap_b32 %0, %1" : "+v"(q1_), "+v"(q3_));                \
    bb[kp].u[0] = q0_;                                                         \
    bb[kp].u[1] = q1_;                                                         \
    bb[kp].u[2] = q2_;                                                         \
    bb[kp].u[3] = q3_;                                                         \
  }

  // prologue: DMA K_0 into buf0
  dma16(kgp + kgl0, smem + w2 * 1024);
  dma16(kgp + kgl1, smem + (w2 + 1) * 1024);
  kgp += 16384;

  // iter 0: S(K_0) from buf0, DMA K_1 + V_0 into buf1 (no V-MFMA yet)
  __syncthreads();
  dma16(kgp + kgl0, smem + 32768 + w2 * 1024);
  dma16(kgp + kgl1, smem + 32768 + (w2 + 1) * 1024);
  kgp += 16384;
  dma16(vgp + vgl0, smem + 32768 + 16384 + w2 * 1024);
  dma16(vgp + vgl1, smem + 32768 + 16384 + (w2 + 1) * 1024);
  vgp += 64;
  {
    f16v S;
#pragma unroll
    for (int r = 0; r < 16; ++r) S[r] = 0.f;
#pragma unroll
    for (int kt = 0; kt < 16; ++kt) {
      bfrag a = *(const bfrag*)(smem + koff[kt & 3] + kt * 1024);
      S = __builtin_amdgcn_mfma_f32_32x32x16_bf16(a, qf[kt], S, 0, 0, 0);
    }
    float ss = 0.f;
#pragma unroll
    for (int r = 0; r < 16; ++r) { float e = exp2f(S[r] - 8.f); S[r] = e; ss += e; }
    l_run += ss;
    PACK_BB(0)
    PACK_BB(1)
  }

// one pipelined iteration with compile-time buffer parity.
// reads K_t (buf BUF) + V_{t-1} (buf BUF); DMAs K_{t+1}+V_t into buf BUF^1.
// the barrier at the top drains last iter's DMAs (implicit vmcnt(0)).
#define ATTN_ITER(BUF, KLOAD)                                                  \
  {                                                                            \
    __syncthreads();                                                           \
    if (KLOAD) {                                                               \
      dma16(kgp + kgl0, smem + ((BUF) ^ 1) * 32768 + w2 * 1024);               \
      dma16(kgp + kgl1, smem + ((BUF) ^ 1) * 32768 + (w2 + 1) * 1024);         \
      kgp += 16384;                                                            \
    }                                                                          \
    dma16(vgp + vgl0, smem + ((BUF) ^ 1) * 32768 + 16384 + w2 * 1024);         \
    dma16(vgp + vgl1, smem + ((BUF) ^ 1) * 32768 + 16384 + (w2 + 1) * 1024);   \
    vgp += 64;                                                                 \
    f16v S;                                                                    \
    _Pragma("unroll")                                                          \
    for (int r = 0; r < 16; ++r) S[r] = 0.f;                                   \
    _Pragma("unroll")                                                          \
    for (int kt = 0; kt < 16; ++kt) {                                          \
      bfrag a = *(const bfrag*)(smem + koff[kt & 3] + ((BUF)*32768 + kt*1024));\
      S = __builtin_amdgcn_mfma_f32_32x32x16_bf16(a, qf[kt], S, 0, 0, 0);      \
      bfrag va = *(const bfrag*)(smem + voff[kt >> 3] +                        \
                                 ((BUF)*32768 + (kt & 7) * 512));              \
      O[kt & 7] = __builtin_amdgcn_mfma_f32_32x32x16_bf16(va, bb[kt >> 3].f,   \
                                                          O[kt & 7], 0, 0, 0); \
    }                                                                          \
    float ss = 0.f;                                                            \
    _Pragma("unroll")                                                          \
    for (int r = 0; r < 16; ++r) { float e = exp2f(S[r] - 8.f); S[r] = e; ss += e; } \
    l_run += ss;                                                               \
    PACK_BB(0)                                                                 \
    PACK_BB(1)                                                                 \
  }

  // t = 1..126 as 63 static-parity pairs, then t = 127.
  for (int tp = 0; tp < 63; ++tp) {
    ATTN_ITER(1, 1)     // odd t
    ATTN_ITER(0, 1)     // even t
  }
  ATTN_ITER(1, 0)       // t = 127: no K prefetch; V_127 DMA'd into buf0
#undef ATTN_ITER

  // epilogue: V-MFMA for tile 127 (buf0 V half)
  __syncthreads();
#pragma unroll
  for (int kp = 0; kp < 2; ++kp) {
#pragma unroll
    for (int mt = 0; mt < 8; ++mt) {
      bfrag va = *(const bfrag*)(smem + voff[kp] + mt * 512);
      O[mt] = __builtin_amdgcn_mfma_f32_32x32x16_bf16(va, bb[kp].f, O[mt], 0, 0, 0);
    }
  }
#undef PACK_BB

  // attc[bh][q][e] = O^T[e][q]/l.  l = own-half + partner-half.
  l_run += __shfl_xor(l_run, 32);
  float rl = 1.0f / l_run;
  short* orow = attc + ((long)bh * 4096 + q0 + ln) * 256;
#pragma unroll
  for (int mt = 0; mt < 8; ++mt) {
#pragma unroll
    for (int g = 0; g < 4; ++g) {
      uint2 st;
      st.x = pkbf(O[mt][4 * g + 0] * rl, O[mt][4 * g + 1] * rl);
      st.y = pkbf(O[mt][4 * g + 2] * rl, O[mt][4 * g + 3] * rl);
      *(uint2*)(orow + mt * 32 + 8 * g + 4 * half) = st;
    }
  }
}

// ---------------------------------------------------------------------------
// FFN head (all fp32): 16 rows per 256-thr block, 4 rows per wave.
// x/h stored transposed in LDS ([k][4rows]) so one broadcast ds_read_b128
// feeds 4 rows; W1/W2 loads amortized 4x. Per-wave buffers -> no barriers.
// ---------------------------------------------------------------------------
__global__ __launch_bounds__(256) void ffn_kernel(
    const float* __restrict__ emb,
    const float* __restrict__ W1, const float* __restrict__ b1,
    const float* __restrict__ g1, const float* __restrict__ be1,
    const float* __restrict__ W2, const float* __restrict__ b2,
    const float* __restrict__ g2, const float* __restrict__ be2,
    const float* __restrict__ W3, const float* __restrict__ b3,
    float* __restrict__ act)
{
  __shared__ float xs[4][256][4];   // [wave][k][row]  16KB
  __shared__ float hs[4][128][4];   // [wave][k][row]   8KB
  int w = threadIdx.x >> 6, l = threadIdx.x & 63;
  int row0 = blockIdx.x * 16 + w * 4;
  const float* x = emb + (long)row0 * 256;

  // load 4 rows, store transposed: lane l owns positions 4l..4l+3
  {
    float xv[4][4];   // [i][row]
#pragma unroll
    for (int rr = 0; rr < 4; ++rr) {
      float4 t = *(const float4*)(x + rr * 256 + 4 * l);
      xv[0][rr] = t.x; xv[1][rr] = t.y; xv[2][rr] = t.z; xv[3][rr] = t.w;
    }
#pragma unroll
    for (int i = 0; i < 4; ++i) {
      float4 st = make_float4(xv[i][0], xv[i][1], xv[i][2], xv[i][3]);
      *(float4*)&xs[w][4 * l + i][0] = st;
    }
  }

  // layer 1: 128 outputs, lane l owns outputs 2l, 2l+1, 4 rows each
  float a0[4], a1[4];
  {
    float bb0 = b1[2 * l], bb1 = b1[2 * l + 1];
#pragma unroll
    for (int rr = 0; rr < 4; ++rr) { a0[rr] = bb0; a1[rr] = bb1; }
  }
  for (int k = 0; k < 256; ++k) {
    float w0 = W1[k * 128 + 2 * l], w1 = W1[k * 128 + 2 * l + 1];
    float4 xv = *(const float4*)&xs[w][k][0];
    a0[0] += xv.x * w0; a1[0] += xv.x * w1;
    a0[1] += xv.y * w0; a1[1] += xv.y * w1;
    a0[2] += xv.z * w0; a1[2] += xv.z * w1;
    a0[3] += xv.w * w0; a1[3] += xv.w * w1;
  }
  {
    float gg0 = g1[2 * l], gg1 = g1[2 * l + 1];
    float ee0 = be1[2 * l], ee1 = be1[2 * l + 1];
    float n0v[4], n1v[4];
#pragma unroll
    for (int rr = 0; rr < 4; ++rr) {
      float u0 = fmaxf(a0[rr], 0.f), u1 = fmaxf(a1[rr], 0.f);
      float s1 = wred(u0 + u1);
      float s2 = wred(u0 * u0 + u1 * u1);
      float mu = s1 * (1.f / 128.f);
      float var = fmaxf(s2 * (1.f / 128.f) - mu * mu, 0.f);
      float rs = rsqrtf(var + 1e-5f);
      n0v[rr] = (u0 - mu) * rs * gg0 + ee0;
      n1v[rr] = (u1 - mu) * rs * gg1 + ee1;
    }
    *(float4*)&hs[w][2 * l][0]     = make_float4(n0v[0], n0v[1], n0v[2], n0v[3]);
    *(float4*)&hs[w][2 * l + 1][0] = make_float4(n1v[0], n1v[1], n1v[2], n1v[3]);
  }

  // layer 2: 64 outputs, lane l owns output l, 4 rows
  float c0[4];
  {
    float bb2 = b2[l];
#pragma unroll
    for (int rr = 0; rr < 4; ++rr) c0[rr] = bb2;
  }
  for (int k = 0; k < 128; ++k) {
    float w2 = W2[k * 64 + l];
    float4 hv = *(const float4*)&hs[w][k][0];
    c0[0] += hv.x * w2;
    c0[1] += hv.y * w2;
    c0[2] += hv.z * w2;
    c0[3] += hv.w * w2;
  }
  {
    float gg2 = g2[l], ee2 = be2[l], w3 = W3[l], bb3 = b3[0];
#pragma unroll
    for (int rr = 0; rr < 4; ++rr) {
      float u = fmaxf(c0[rr], 0.f);
      float t1 = wred(u);
      float t2 = wred(u * u);
      float mu2 = t1 * (1.f / 64.f);
      float var2 = fmaxf(t2 * (1.f / 64.f) - mu2 * mu2, 0.f);
      float rs2 = rsqrtf(var2 + 1e-5f);
      float n2 = (u - mu2) * rs2 * gg2 + ee2;
      float tt = wred(n2 * w3);
      if (l == 0) {
        float r = tt + bb3;
        act[row0 + rr] = 1.f / (1.f + __expf(-r));
      }
    }
  }
}

// ---------------------------------------------------------------------------
extern "C" void kernel_launch(void* const* d_in, const int* in_sizes, int n_in,
                              void* d_out, int out_size, void* d_ws, size_t ws_size,
                              hipStream_t stream)
{
  const float* img_emb   = (const float*)d_in[0];
  const float* point_emb = (const float*)d_in[1];
  const float* Wq = (const float*)d_in[2];
  const float* bq = (const float*)d_in[3];
  const float* Wk = (const float*)d_in[4];
  const float* bk = (const float*)d_in[5];
  const float* Wv = (const float*)d_in[6];
  const float* bv = (const float*)d_in[7];
  const float* Wo = (const float*)d_in[8];
  const float* bo = (const float*)d_in[9];
  const float* pos = (const float*)d_in[10];
  const float* W1 = (const float*)d_in[11];
  const float* b1 = (const float*)d_in[12];
  const float* g1 = (const float*)d_in[13];
  const float* be1 = (const float*)d_in[14];
  const float* W2 = (const float*)d_in[15];
  const float* b2 = (const float*)d_in[16];
  const float* g2 = (const float*)d_in[17];
  const float* be2 = (const float*)d_in[18];
  const float* W3 = (const float*)d_in[19];
  const float* b3 = (const float*)d_in[20];

  // ws layout (111.1 MB), all internal tensors bf16.
  // peT/imgT live INSIDE the VtB region: both are dead before the V-gemm
  // (the only writer of VtB) runs — stream order guarantees safety.
  // (Do NOT merge the three qkv GEMM launches: that ordering is load-bearing.)
  char* ws = (char*)d_ws;
  short* Qb      = (short*)(ws + 0);            // 33.55 MB [BH][4096][256]; attn out in-place
  short* Kb      = (short*)(ws + 33554432);     // 33.55 MB [BH][4096][256]
  short* VtB     = (short*)(ws + 67108864);     // 33.55 MB [BH][256][4096]
  short* peT     = (short*)(ws + 67108864);     //  8.39 MB [B][4096][256]  (dead after Q-gemm)
  short* imgT    = (short*)(ws + 75497472);     //  8.39 MB [B][4096][256]  (dead after K-gemm)
  short* imgPosT = (short*)(ws + 100663296);    //  8.39 MB [B][4096][256]
  short* WoT     = (short*)(ws + 109051904);    //  0.52 MB [256][1024]
  short* WqT     = (short*)(ws + 109576192);    //  0.13 MB [H][256][256]  (WkT,WvT follow)
  short* WkT     = (short*)(ws + 110100480);
  short* WvT     = (short*)(ws + 110624768);
  (void)WkT; (void)WvT;

  float* act_out = (float*)d_out;            // [B*N]
  float* emb_out = (float*)d_out + 16384;    // [B*N][256]

  const float qscale = 0.0901684400555602f;  // log2(e)/sqrt(256)

  // fused prep: all weight transposes + img transpose/pos-add + point_emb cast
  prep_kernel<<<3328, 256, 0, stream>>>(point_emb, peT, img_emb, pos,
                                        imgT, imgPosT, Wq, Wk, Wv, WqT, Wo, WoT);

  // Q = (point_emb @ WqT + bq) * qscale      (reads peT — before VtB written)
  gemm_qkv<<<dim3(32, 4, 16), 256, 0, stream>>>(peT, WqT, bq, Qb, qscale, 0);
  // K = img @ WkT + bk                       (reads imgT — before VtB written)
  gemm_qkv<<<dim3(32, 4, 16), 256, 0, stream>>>(imgT, WqT + 262144, bk, Kb, 1.0f, 0);
  // V^T = ((img + pos) @ WvT + bv)^T         (reads imgPosT, writes VtB)
  gemm_qkv<<<dim3(32, 4, 16), 256, 0, stream>>>(imgPosT, WqT + 524288, bv, VtB, 1.0f, 1);

  // attention: reads Qb/Kb/VtB, writes att in-place over Qb ([BH][N][256])
  attn_kernel<<<256, 512, 0, stream>>>(Qb, Kb, VtB, Qb);

  // emb = att @ Wo + bo + point_emb  (fp32 out)
  gemm_out<<<dim3(128, 4, 1), 256, 0, stream>>>(Qb, WoT, bo, emb_out, point_emb);

  // FFN head -> act (fp32)
  ffn_kernel<<<1024, 256, 0, stream>>>(emb_out, W1, b1, g1, be1, W2, b2, g2, be2,
                                       W3, b3, act_out);
}